// Round 12
// baseline (140.357 us; speedup 1.0000x reference)
//
#include <hip/hip_runtime.h>

#define B_ 32
#define C_ 64
#define N_ 2048
#define H_ 128
#define MSHIFT 12.0f   // fixed log2-domain shift; softmax is shift-invariant (exact)

typedef unsigned short u16;
typedef unsigned int u32;
typedef float f32x4 __attribute__((ext_vector_type(4)));
typedef float f32x16 __attribute__((ext_vector_type(16)));
typedef __bf16 bf16x8 __attribute__((ext_vector_type(8)));
typedef __bf16 bf16x4 __attribute__((ext_vector_type(4)));
typedef unsigned short u16x4 __attribute__((ext_vector_type(4)));
typedef unsigned int u32x4v __attribute__((ext_vector_type(4)));

#define MFMA(a, b, c) __builtin_amdgcn_mfma_f32_16x16x32_bf16(a, b, c, 0, 0, 0)
#define MFMA32(a, b, c) __builtin_amdgcn_mfma_f32_32x32x16_bf16(a, b, c, 0, 0, 0)
#define EXP2(x) __builtin_amdgcn_exp2f(x)
#define LOG2E 1.44269504088896f

// XOR swizzle for 128-byte-stride LDS rows (bf16 [*][64]); returns BYTE offset.
__device__ __forceinline__ int swz(int row, int cb) { return row * 128 + (cb ^ ((row & 7) << 4)); }
// same for 256-byte-stride rows (bf16 [*][128])
__device__ __forceinline__ int swz256(int row, int cb) { return row * 256 + (cb ^ ((row & 7) << 4)); }

__device__ __forceinline__ float b2f(u16 v) {
    union { u32 u; float f; } x; x.u = ((u32)v) << 16; return x.f;
}

__device__ __forceinline__ u32 cvtpk(float lo, float hi) {
    u32 r;
    asm("v_cvt_pk_bf16_f32 %0, %1, %2" : "=v"(r) : "v"(lo), "v"(hi));
    return r;
}

// Build PV B-fragment (k=8*hi+e over a 16-m chunk) from 8 per-lane P values.
// lane<32 holds m{0..3}=p0..3, m{8..11}=p4..7; lane>=32 holds m{4..7}, m{12..15}.
__device__ __forceinline__ bf16x8 pfrag(float p0, float p1, float p2, float p3,
                                        float p4, float p5, float p6, float p7) {
    u32 x1 = cvtpk(p0, p1), x2 = cvtpk(p2, p3);
    u32 y1 = cvtpk(p4, p5), y2 = cvtpk(p6, p7);
    asm volatile("v_permlane32_swap_b32 %0, %1" : "+v"(x1), "+v"(y1));
    asm volatile("v_permlane32_swap_b32 %0, %1" : "+v"(x2), "+v"(y2));
    u32x4v d; d[0] = x1; d[1] = x2; d[2] = y1; d[3] = y2;
    return __builtin_bit_cast(bf16x8, d);
}

__device__ __forceinline__ bf16x8 cvt8(const float* p, float s) {
    f32x4 a = *(const f32x4*)p, b = *(const f32x4*)(p + 4);
    bf16x8 o;
    o[0] = (__bf16)(a[0] * s); o[1] = (__bf16)(a[1] * s);
    o[2] = (__bf16)(a[2] * s); o[3] = (__bf16)(a[3] * s);
    o[4] = (__bf16)(b[0] * s); o[5] = (__bf16)(b[1] * s);
    o[6] = (__bf16)(b[2] * s); o[7] = (__bf16)(b[3] * s);
    return o;
}

// ---------------------------------------------------------------------------
// Kernel 1: Q = (0.125*log2e)*wq*x ([B,N,C] bf16), K = wk*x ([B,N,C]),
// V = wv*x ([B,C,N]).  All D-fragments oriented so stores are bf16x4.
// ---------------------------------------------------------------------------
__global__ __launch_bounds__(256) void qkv_k(
    const float* __restrict__ x,
    const float* __restrict__ wq, const float* __restrict__ wk, const float* __restrict__ wv,
    const float* __restrict__ w1, const float* __restrict__ w2,
    u16* __restrict__ Qg, u16* __restrict__ Kg, u16* __restrict__ Vg,
    u16* __restrict__ w1b, u16* __restrict__ w2b)
{
    const int b = blockIdx.y, nt = blockIdx.x, t = threadIdx.x;
    const int lane = t & 63, wave = t >> 6, g = lane >> 4, r16 = lane & 15;
    __shared__ __align__(16) u16 xT[128 * 64];   // swizzled bf16 [n_local][c]
    const int n0 = nt * 128;

    bf16x8 wqf[4][2], wkf[4][2], wvf[4][2];
#pragma unroll
    for (int jt = 0; jt < 4; ++jt)
#pragma unroll
        for (int kc = 0; kc < 2; ++kc) {
            const int ro = (r16 + 16 * jt) * 64 + 8 * g + 32 * kc;
            wqf[jt][kc] = cvt8(wq + ro, 0.125f * LOG2E);  // fold 1/sqrt(C) and log2(e)
            wkf[jt][kc] = cvt8(wk + ro, 1.0f);
            wvf[jt][kc] = cvt8(wv + ro, 1.0f);
        }

    { // stage x tile transposed (n-major) + swizzled, as bf16
        int c = t >> 5;
        const int nn = (t & 31) * 4;
#pragma unroll
        for (int pass = 0; pass < 8; ++pass, c += 8) {
            f32x4 v = *(const f32x4*)&x[(size_t)(b * 64 + c) * 2048 + n0 + nn];
#pragma unroll
            for (int j = 0; j < 4; ++j)
                xT[swz(nn + j, 2 * c) >> 1] = __builtin_bit_cast(u16, (__bf16)v[j]);
        }
    }
    if (b == 0 && nt == 0) {
        for (int i = t; i < H_ * C_; i += 256) w1b[i] = __builtin_bit_cast(u16, (__bf16)w1[i]);
        for (int i = t; i < C_ * H_; i += 256) w2b[i] = __builtin_bit_cast(u16, (__bf16)w2[i]);
    }
    __syncthreads();

#pragma unroll
    for (int p = 0; p < 2; ++p) {
        const int nt16 = wave * 2 + p;
        bf16x8 xa[2];  // x^T tile frag: A (i=n) or B (j=n)
#pragma unroll
        for (int kc = 0; kc < 2; ++kc)
            xa[kc] = *(const bf16x8*)&xT[swz(nt16 * 16 + r16, 16 * g + 64 * kc) >> 1];
        // Q,K: D[o][n] -> row o = 16jt+4g+r, col n = r16 -> vector store along o
#pragma unroll
        for (int jt = 0; jt < 4; ++jt) {
            f32x4 aq = {0.f, 0.f, 0.f, 0.f}, ak = {0.f, 0.f, 0.f, 0.f};
            aq = MFMA(wqf[jt][0], xa[0], aq); aq = MFMA(wqf[jt][1], xa[1], aq);
            ak = MFMA(wkf[jt][0], xa[0], ak); ak = MFMA(wkf[jt][1], xa[1], ak);
            bf16x4 qk, kk;
#pragma unroll
            for (int r = 0; r < 4; ++r) { qk[r] = (__bf16)aq[r]; kk[r] = (__bf16)ak[r]; }
            const size_t ro = (size_t)(b * 2048 + n0 + nt16 * 16 + r16) * 64 + 16 * jt + 4 * g;
            *(bf16x4*)&Qg[ro] = qk;
            *(bf16x4*)&Kg[ro] = kk;
        }
        // V: D[n][o] -> row n = nt16*16+4g+r, col o = 16it+r16 -> vector store along n
#pragma unroll
        for (int it = 0; it < 4; ++it) {
            f32x4 av = {0.f, 0.f, 0.f, 0.f};
            av = MFMA(xa[0], wvf[it][0], av);
            av = MFMA(xa[1], wvf[it][1], av);
            bf16x4 vk;
#pragma unroll
            for (int r = 0; r < 4; ++r) vk[r] = (__bf16)av[r];
            *(bf16x4*)&Vg[(size_t)(b * 64 + 16 * it + r16) * 2048 + n0 + nt16 * 16 + 4 * g] = vk;
        }
    }
}

// ---------------------------------------------------------------------------
// Kernel 2: flash attention, 32x32x16 MFMA, fixed-shift softmax, kv-split
// within the block.  256 blocks x 512 threads (1 block/CU = 2 waves/SIMD).
// Waves 0-3: kv 0..1023; waves 4-7: kv 1024..2047.  Wave pair (w, w+4) owns
// the same 64 q rows (2 groups of 32 sharing one K/V fragment set -> 16 LDS
// reads serve 32 MFMAs).  Each half streams its own K/V 32KB double-buffer.
// Fixed-shift softmax has NO online state -> partial acc/lp are plain sums;
// half-1 publishes partials via LDS (staging area, dead after loop) and
// half-0 combines + runs the epilogue.
// Epilogue: y(bf16) = x + O/l + fused BN1 partials.
// ---------------------------------------------------------------------------
__global__ __launch_bounds__(512, 2) void attn_k(
    const u16* __restrict__ Qg, const u16* __restrict__ Kg, const u16* __restrict__ Vg,
    const float* __restrict__ x, u16* __restrict__ yb,
    float* __restrict__ ps, float* __restrict__ pq)
{
    const int t = threadIdx.x;
    const int lane = t & 63, wave = t >> 6;        // wave 0..7
    const int wq4 = wave & 3, half = wave >> 2;    // q-segment, kv-half
    const int q = lane & 31, hi = lane >> 5;
    const int L = blockIdx.x;              // 0..255
    const int xcd = L & 7, slot = L >> 3;  // slot 0..31
    const int b = xcd * 4 + (slot >> 3);
    const int qt = slot & 7;               // q tile of 256 rows

    // bytes: half h staging @ h*32768: K0@0 K1@8192 V0@16384 V1@24576 (64KB);
    // lp spill @65536 (2KB).  Staging reused for acc-combine + stats after loop.
    __shared__ __align__(16) u16 Lds16[33792];     // 67.5 KB
    char* lds = (char*)Lds16;
    char* ldsh = lds + half * 32768;

    const int n0 = qt * 256 + wq4 * 64;    // this wave-pair's 64 q rows

    // Q B-frags for both groups: Q[n0 + 32u + q][c = 16kc + 8hi + e]
    bf16x8 qf[2][4];
#pragma unroll
    for (int u = 0; u < 2; ++u) {
        const u16* qrow = Qg + (size_t)(b * 2048 + n0 + 32 * u + q) * 64 + 8 * hi;
#pragma unroll
        for (int kc = 0; kc < 4; ++kc)
            qf[u][kc] = *(const bf16x8*)(qrow + 16 * kc);
    }

    f32x16 acc[2][2];
#pragma unroll
    for (int u = 0; u < 2; ++u)
#pragma unroll
        for (int ct = 0; ct < 2; ++ct)
#pragma unroll
            for (int r = 0; r < 16; ++r) acc[u][ct][r] = 0.f;
    float lp[2] = {0.f, 0.f};

    const char* Kgb = (const char*)Kg + (size_t)b * 2048 * 128 + (size_t)half * 1024 * 128;
    const char* Vgb = (const char*)Vg + (size_t)b * 64 * 4096 + half * 2048;
    const int srcxor = (((lane & 7) ^ (lane >> 3)) << 4);
    const int rowb = wq4 * 16 + (lane >> 3);

    auto stage = [&](int kvt, int buf) {
#pragma unroll
        for (int j = 0; j < 2; ++j) {
            const char* gk = Kgb + (size_t)(kvt * 64 + rowb + 8 * j) * 128 + srcxor;
            const char* gv = Vgb + (size_t)(rowb + 8 * j) * 4096 + kvt * 128 + srcxor;
            char* lk = ldsh + buf * 8192 + (wq4 * 2 + j) * 1024;
            __builtin_amdgcn_global_load_lds(
                (const __attribute__((address_space(1))) void*)gk,
                (__attribute__((address_space(3))) void*)lk, 16, 0, 0);
            __builtin_amdgcn_global_load_lds(
                (const __attribute__((address_space(1))) void*)gv,
                (__attribute__((address_space(3))) void*)(lk + 16384), 16, 0, 0);
        }
    };

    auto tile = [&](int kvt, int buf) {
        __syncthreads();                 // buf ready (vmcnt drained at barrier)
        if (kvt + 1 < 16) stage(kvt + 1, buf ^ 1);
        const char* Kc = ldsh + buf * 8192;
        const char* Vc = Kc + 16384;

        // K and V A-frags — one set serves both q-groups
        bf16x8 kf[8], vf[8];
#pragma unroll
        for (int i = 0; i < 8; ++i)
            kf[i] = *(const bf16x8*)(Kc + swz(32 * (i >> 2) + q, 32 * (i & 3) + 16 * hi));
#pragma unroll
        for (int i = 0; i < 8; ++i)
            vf[i] = *(const bf16x8*)(Vc + swz(32 * (i >> 2) + q, 32 * (i & 3) + 16 * hi));

        // QK^T both groups, C-init = -MSHIFT (log2 domain)
        f32x16 st[2][2];
        __builtin_amdgcn_s_setprio(1);
#pragma unroll
        for (int u = 0; u < 2; ++u)
#pragma unroll
            for (int it = 0; it < 2; ++it) {
                f32x16 a;
#pragma unroll
                for (int r = 0; r < 16; ++r) a[r] = -MSHIFT;
#pragma unroll
                for (int kc = 0; kc < 4; ++kc)
                    a = MFMA32(kf[4 * it + kc], qf[u][kc], a);
                st[u][it] = a;
            }
        __builtin_amdgcn_s_setprio(0);

        // per group: exp2 + VALU tree sum + reg-only P frags + PV
#pragma unroll
        for (int u = 0; u < 2; ++u) {
#pragma unroll
            for (int it = 0; it < 2; ++it)
#pragma unroll
                for (int r = 0; r < 16; ++r) st[u][it][r] = EXP2(st[u][it][r]);
            float ls = 0.f;
#pragma unroll
            for (int it = 0; it < 2; ++it) {
                float a0 = (st[u][it][0] + st[u][it][1]) + (st[u][it][2] + st[u][it][3]);
                float a1 = (st[u][it][4] + st[u][it][5]) + (st[u][it][6] + st[u][it][7]);
                float a2 = (st[u][it][8] + st[u][it][9]) + (st[u][it][10] + st[u][it][11]);
                float a3 = (st[u][it][12] + st[u][it][13]) + (st[u][it][14] + st[u][it][15]);
                ls += (a0 + a1) + (a2 + a3);
            }
            lp[u] += ls;
            bf16x8 pf0 = pfrag(st[u][0][0], st[u][0][1], st[u][0][2], st[u][0][3],
                               st[u][0][4], st[u][0][5], st[u][0][6], st[u][0][7]);
            bf16x8 pf1 = pfrag(st[u][0][8], st[u][0][9], st[u][0][10], st[u][0][11],
                               st[u][0][12], st[u][0][13], st[u][0][14], st[u][0][15]);
            bf16x8 pf2 = pfrag(st[u][1][0], st[u][1][1], st[u][1][2], st[u][1][3],
                               st[u][1][4], st[u][1][5], st[u][1][6], st[u][1][7]);
            bf16x8 pf3 = pfrag(st[u][1][8], st[u][1][9], st[u][1][10], st[u][1][11],
                               st[u][1][12], st[u][1][13], st[u][1][14], st[u][1][15]);
            __builtin_amdgcn_s_setprio(1);
#pragma unroll
            for (int ct = 0; ct < 2; ++ct) {
                acc[u][ct] = MFMA32(vf[4 * ct + 0], pf0, acc[u][ct]);
                acc[u][ct] = MFMA32(vf[4 * ct + 1], pf1, acc[u][ct]);
                acc[u][ct] = MFMA32(vf[4 * ct + 2], pf2, acc[u][ct]);
                acc[u][ct] = MFMA32(vf[4 * ct + 3], pf3, acc[u][ct]);
            }
            __builtin_amdgcn_s_setprio(0);
        }
    };

    stage(0, 0);
#pragma unroll 1
    for (int kvt = 0; kvt < 16; kvt += 2) {
        tile(kvt, 0);
        tile(kvt + 1, 1);
    }

    // ---- combine halves via LDS (staging area is dead now) ----
    __syncthreads();                       // everyone done reading K/V
    float* lpb = (float*)(lds + 65536);
    if (half == 1) {
        char* base = lds + wq4 * 16384 + lane * 256;
#pragma unroll
        for (int u = 0; u < 2; ++u)
#pragma unroll
            for (int ct = 0; ct < 2; ++ct)
#pragma unroll
                for (int p = 0; p < 4; ++p) {
                    f32x4 v4;
#pragma unroll
                    for (int j = 0; j < 4; ++j) v4[j] = acc[u][ct][4 * p + j];
                    *(f32x4*)(base + (u * 2 + ct) * 64 + p * 16) = v4;
                }
        lpb[(wq4 * 64 + lane) * 2 + 0] = lp[0];
        lpb[(wq4 * 64 + lane) * 2 + 1] = lp[1];
    }
    __syncthreads();
    if (half == 0) {
        const char* base = lds + wq4 * 16384 + lane * 256;
#pragma unroll
        for (int u = 0; u < 2; ++u)
#pragma unroll
            for (int ct = 0; ct < 2; ++ct)
#pragma unroll
                for (int p = 0; p < 4; ++p) {
                    f32x4 v4 = *(const f32x4*)(base + (u * 2 + ct) * 64 + p * 16);
#pragma unroll
                    for (int j = 0; j < 4; ++j) acc[u][ct][4 * p + j] += v4[j];
                }
        lp[0] += lpb[(wq4 * 64 + lane) * 2 + 0];
        lp[1] += lpb[(wq4 * 64 + lane) * 2 + 1];
    }

    // epilogue (half-0 waves do the work; half-1 contributes zeros to stats)
    float inv[2];
#pragma unroll
    for (int u = 0; u < 2; ++u) {
        const float l = lp[u] + __shfl_xor(lp[u], 32, 64);
        inv[u] = 1.0f / l;
    }
    float sv[2][16], qv[2][16];
#pragma unroll
    for (int ct = 0; ct < 2; ++ct)
#pragma unroll
        for (int r = 0; r < 16; ++r) { sv[ct][r] = 0.f; qv[ct][r] = 0.f; }
    if (half == 0) {
#pragma unroll
        for (int u = 0; u < 2; ++u) {
            const int n = n0 + 32 * u + q;
#pragma unroll
            for (int ct = 0; ct < 2; ++ct)
#pragma unroll
                for (int grp = 0; grp < 4; ++grp) {
                    bf16x4 ov;
#pragma unroll
                    for (int j = 0; j < 4; ++j) {
                        const int r = 4 * grp + j;
                        const int c = 32 * ct + j + 8 * grp + 4 * hi;
                        const float o = acc[u][ct][r] * inv[u] + x[(size_t)(b * 64 + c) * 2048 + n];
                        sv[ct][r] += o;
                        qv[ct][r] += o * o;
                        ov[j] = (__bf16)o;
                    }
                    *(bf16x4*)&yb[(size_t)(b * 2048 + n) * 64 + 32 * ct + 8 * grp + 4 * hi] = ov;
                }
        }
    }
    // reduce stats across lane&31 (hi kept separate); half-1 lanes hold zeros
#pragma unroll
    for (int d = 1; d <= 16; d <<= 1)
#pragma unroll
        for (int ct = 0; ct < 2; ++ct)
#pragma unroll
            for (int r = 0; r < 16; ++r) {
                sv[ct][r] += __shfl_xor(sv[ct][r], d, 64);
                qv[ct][r] += __shfl_xor(qv[ct][r], d, 64);
            }
    __syncthreads();                       // combine area no longer needed
    float* sb = (float*)lds;               // [0..511]=sum, [512..1023]=sumsq
    if (q == 0) {
#pragma unroll
        for (int ct = 0; ct < 2; ++ct)
#pragma unroll
            for (int r = 0; r < 16; ++r) {
                const int c = 32 * ct + (r & 3) + 8 * (r >> 2) + 4 * hi;
                sb[wave * 64 + c] = sv[ct][r];
                sb[512 + wave * 64 + c] = qv[ct][r];
            }
    }
    __syncthreads();
    if (t < 64) {
        float s = 0.f, qq = 0.f;
#pragma unroll
        for (int w = 0; w < 8; ++w) { s += sb[w * 64 + t]; qq += sb[512 + w * 64 + t]; }
        ps[L * 64 + t] = s;
        pq[L * 64 + t] = qq;
    }
}

// ---------------------------------------------------------------------------
// finalize: 64 blocks (one channel each) sum nblk partials -> scale/shift
// ---------------------------------------------------------------------------
__global__ __launch_bounds__(256) void finalize_k(
    const float* __restrict__ psum, const float* __restrict__ psq,
    const float* __restrict__ gamma, const float* __restrict__ beta,
    float* __restrict__ ss, int nblk)
{
    const int c = blockIdx.x, t = threadIdx.x;
    const int lane = t & 63, wave = t >> 6;
    float s = 0.f, q = 0.f;
    for (int bl = t; bl < nblk; bl += 256) {
        s += psum[bl * 64 + c];
        q += psq[bl * 64 + c];
    }
#pragma unroll
    for (int d = 1; d <= 32; d <<= 1) {
        s += __shfl_xor(s, d, 64);
        q += __shfl_xor(q, d, 64);
    }
    __shared__ float ls[4], lq[4];
    if (lane == 0) { ls[wave] = s; lq[wave] = q; }
    __syncthreads();
    if (t == 0) {
        s = ls[0] + ls[1] + ls[2] + ls[3];
        q = lq[0] + lq[1] + lq[2] + lq[3];
        const float mean = s * (1.0f / 65536.0f);
        const float var  = q * (1.0f / 65536.0f) - mean * mean;
        const float sc   = rsqrtf(var + 1e-5f) * gamma[c];
        ss[c] = sc;
        ss[64 + c] = beta[c] - mean * sc;
    }
}

// ---------------------------------------------------------------------------
// Kernel: h = BN1(y_bf16); ff = W2 * lrelu(W1 * h); z(bf16) = h + ff
// plus fused BN2 partial sums (from exact f32 registers).
// ---------------------------------------------------------------------------
__global__ __launch_bounds__(256) void ff_k(
    const u16* __restrict__ y, const float* __restrict__ ss1,
    const u16* __restrict__ w1b, const u16* __restrict__ w2b,
    u16* __restrict__ zb, float* __restrict__ ps, float* __restrict__ pq)
{
    const int b = blockIdx.y, nt = blockIdx.x, t = threadIdx.x;
    const int lane = t & 63, wave = t >> 6, g = lane >> 4, r16 = lane & 15;
    const int L = blockIdx.y * gridDim.x + blockIdx.x;
    __shared__ __align__(16) u16 hT[64 * 64];       // swizzled bf16 [n][c]
    __shared__ __align__(16) float hf[64 * 68];     // f32 [n][c], pad 68
    __shared__ __align__(16) u16 pb[4][16 * 128];   // per-wave swizzled [n][h]
    __shared__ float sc1[64], sh1[64];
    if (t < 64) { sc1[t] = ss1[t]; sh1[t] = ss1[64 + t]; }
    __syncthreads();
    const int n0 = nt * 64;
    {
        const int i = t >> 2, c0 = (t & 3) * 16;
        u16 yb16[16] __attribute__((aligned(16)));
        *(uint4*)&yb16[0] = *(const uint4*)&y[(size_t)(b * 2048 + n0 + i) * 64 + c0];
        *(uint4*)&yb16[8] = *(const uint4*)&y[(size_t)(b * 2048 + n0 + i) * 64 + c0 + 8];
        u16 hb[16] __attribute__((aligned(16)));
#pragma unroll
        for (int q4 = 0; q4 < 4; ++q4) {
            f32x4 hv;
#pragma unroll
            for (int j = 0; j < 4; ++j) {
                const int c = c0 + 4 * q4 + j;
                hv[j] = b2f(yb16[4 * q4 + j]) * sc1[c] + sh1[c];
                hb[4 * q4 + j] = __builtin_bit_cast(u16, (__bf16)hv[j]);
            }
            *(f32x4*)&hf[i * 68 + c0 + 4 * q4] = hv;
        }
        *(uint4*)&hT[swz(i, 2 * c0) >> 1]      = *(const uint4*)&hb[0];
        *(uint4*)&hT[swz(i, 2 * c0 + 16) >> 1] = *(const uint4*)&hb[8];
    }
    __syncthreads();

    bf16x8 ha[2];
#pragma unroll
    for (int kc = 0; kc < 2; ++kc)
        ha[kc] = *(const bf16x8*)&hT[swz(wave * 16 + r16, 16 * g + 64 * kc) >> 1];
    // ff1 = lrelu(W1 * h), written transposed to pb
#pragma unroll
    for (int it = 0; it < 8; ++it) {
        f32x4 a = {0.f, 0.f, 0.f, 0.f};
#pragma unroll
        for (int kc = 0; kc < 2; ++kc) {
            bf16x8 w1f = *(const bf16x8*)&w1b[(r16 + 16 * it) * 64 + 8 * g + 32 * kc];
            a = MFMA(w1f, ha[kc], a);
        }
        u16x4 pk;
#pragma unroll
        for (int r = 0; r < 4; ++r) {
            const float rv = a[r] >= 0.f ? a[r] : 0.2f * a[r];
            pk[r] = __builtin_bit_cast(u16, (__bf16)rv);
        }
        *(u16x4*)&pb[wave][swz256(r16, 2 * (16 * it + 4 * g)) >> 1] = pk;
    }
    // ff2: D[c][n] (A=w2f, B=pa) -> vector store along c; z = h + ff2
    bf16x8 pa[4];
#pragma unroll
    for (int kc = 0; kc < 4; ++kc)
        pa[kc] = *(const bf16x8*)&pb[wave][swz256(r16, 16 * g + 64 * kc) >> 1];
    const int nl = wave * 16 + r16;
    float sv[4][4], qv[4][4];
#pragma unroll
    for (int jt = 0; jt < 4; ++jt) {
        f32x4 a = {0.f, 0.f, 0.f, 0.f};
#pragma unroll
        for (int kc = 0; kc < 4; ++kc) {
            bf16x8 w2f = *(const bf16x8*)&w2b[(r16 + 16 * jt) * 128 + 8 * g + 32 * kc];
            a = MFMA(w2f, pa[kc], a);
        }
        f32x4 h4 = *(const f32x4*)&hf[nl * 68 + 16 * jt + 4 * g];
        bf16x4 zk;
#pragma unroll
        for (int r = 0; r < 4; ++r) {
            a[r] += h4[r];
            sv[jt][r] = a[r];
            qv[jt][r] = a[r] * a[r];
            zk[r] = (__bf16)a[r];
        }
        *(bf16x4*)&zb[(size_t)(b * 2048 + n0 + nl) * 64 + 16 * jt + 4 * g] = zk;
    }
    // fused BN2 partials: reduce over the wave's 16 rows (across r16)
#pragma unroll
    for (int d = 1; d <= 8; d <<= 1)
#pragma unroll
        for (int jt = 0; jt < 4; ++jt)
#pragma unroll
            for (int r = 0; r < 4; ++r) {
                sv[jt][r] += __shfl_xor(sv[jt][r], d, 64);
                qv[jt][r] += __shfl_xor(qv[jt][r], d, 64);
            }
    __syncthreads();                       // all waves done with pb
    float* sb = (float*)&pb[0][0];
    if (r16 == 0) {
#pragma unroll
        for (int jt = 0; jt < 4; ++jt)
#pragma unroll
            for (int r = 0; r < 4; ++r) {
                const int c = 16 * jt + 4 * g + r;
                sb[wave * 64 + c] = sv[jt][r];
                sb[256 + wave * 64 + c] = qv[jt][r];
            }
    }
    __syncthreads();
    if (t < 64) {
        ps[L * 64 + t] = sb[t] + sb[64 + t] + sb[128 + t] + sb[192 + t];
        pq[L * 64 + t] = sb[256 + t] + sb[320 + t] + sb[384 + t] + sb[448 + t];
    }
}

// ---------------------------------------------------------------------------
// Kernel: out[B,C,N] = BN2(z_bf16[B,N,C])  (LDS transpose, f32 output)
// ---------------------------------------------------------------------------
__global__ __launch_bounds__(256) void bnout_k(
    const u16* __restrict__ zb, const float* __restrict__ ss2, float* __restrict__ out)
{
    const int b = blockIdx.y, nt = blockIdx.x, t = threadIdx.x;
    __shared__ float tile[64 * 68];
    __shared__ float sc2[64], sh2[64];
    if (t < 64) { sc2[t] = ss2[t]; sh2[t] = ss2[64 + t]; }
    __syncthreads();
    const int n0 = nt * 64;
    {
        const int i = t >> 2, c0 = (t & 3) * 16;
        u16 zb16[16] __attribute__((aligned(16)));
        *(uint4*)&zb16[0] = *(const uint4*)&zb[(size_t)(b * 2048 + n0 + i) * 64 + c0];
        *(uint4*)&zb16[8] = *(const uint4*)&zb[(size_t)(b * 2048 + n0 + i) * 64 + c0 + 8];
#pragma unroll
        for (int q4 = 0; q4 < 4; ++q4) {
            f32x4 tv;
#pragma unroll
            for (int j = 0; j < 4; ++j) {
                const int c = c0 + 4 * q4 + j;
                tv[j] = b2f(zb16[4 * q4 + j]) * sc2[c] + sh2[c];
            }
            *(f32x4*)&tile[i * 68 + c0 + 4 * q4] = tv;
        }
    }
    __syncthreads();
    {
        const int c = t >> 2, j0 = (t & 3) * 16;
#pragma unroll
        for (int q4 = 0; q4 < 4; ++q4) {
            f32x4 ov;
#pragma unroll
            for (int j = 0; j < 4; ++j)
                ov[j] = tile[(j0 + 4 * q4 + j) * 68 + c];
            *(f32x4*)&out[(size_t)(b * 64 + c) * 2048 + n0 + j0 + 4 * q4] = ov;
        }
    }
}

extern "C" void kernel_launch(void* const* d_in, const int* in_sizes, int n_in,
                              void* d_out, int out_size, void* d_ws, size_t ws_size,
                              hipStream_t stream)
{
    const float* x   = (const float*)d_in[0];
    const float* wq  = (const float*)d_in[1];
    const float* wk  = (const float*)d_in[2];
    const float* wv  = (const float*)d_in[3];
    const float* w1  = (const float*)d_in[4];
    const float* w2  = (const float*)d_in[5];
    const float* g1  = (const float*)d_in[6];
    const float* be1 = (const float*)d_in[7];
    const float* g2  = (const float*)d_in[8];
    const float* be2 = (const float*)d_in[9];
    float* out = (float*)d_out;

    char* w = (char*)d_ws;
    u16* Qg = (u16*)w;   w += (size_t)B_ * N_ * C_ * 2;
    u16* Kg = (u16*)w;   w += (size_t)B_ * N_ * C_ * 2;
    u16* Vg = (u16*)w;   w += (size_t)B_ * N_ * C_ * 2;
    u16* yb = (u16*)w;   w += (size_t)B_ * N_ * C_ * 2;
    u16* zb = (u16*)w;   w += (size_t)B_ * N_ * C_ * 2;
    u16* w1b = (u16*)w;  w += (size_t)H_ * C_ * 2;
    u16* w2b = (u16*)w;  w += (size_t)C_ * H_ * 2;
    float* ps1 = (float*)w; w += 1024 * 64 * 4;
    float* pq1 = (float*)w; w += 1024 * 64 * 4;
    float* ps2 = (float*)w; w += 1024 * 64 * 4;
    float* pq2 = (float*)w; w += 1024 * 64 * 4;
    float* ss1 = (float*)w; w += 128 * 4;
    float* ss2 = (float*)w; w += 128 * 4;

    hipLaunchKernelGGL(qkv_k,   dim3(16, 32), dim3(256), 0, stream, x, wq, wk, wv, w1, w2, Qg, Kg, Vg, w1b, w2b);
    hipLaunchKernelGGL(attn_k,  dim3(256),    dim3(512), 0, stream, Qg, Kg, Vg, x, yb, ps1, pq1);
    hipLaunchKernelGGL(finalize_k, dim3(64),  dim3(256), 0, stream, ps1, pq1, g1, be1, ss1, 256);
    hipLaunchKernelGGL(ff_k,    dim3(32, 32), dim3(256), 0, stream, yb, ss1, w1b, w2b, zb, ps2, pq2);
    hipLaunchKernelGGL(finalize_k, dim3(64),  dim3(256), 0, stream, ps2, pq2, g2, be2, ss2, 1024);
    hipLaunchKernelGGL(bnout_k, dim3(32, 32), dim3(256), 0, stream, zb, ss2, out);
}

// Round 13
// 123.169 us; speedup vs baseline: 1.1396x; 1.1396x over previous
//
#include <hip/hip_runtime.h>

#define B_ 32
#define C_ 64
#define N_ 2048
#define H_ 128
#define MSHIFT 12.0f   // fixed log2-domain shift; softmax is shift-invariant (exact)

typedef unsigned short u16;
typedef unsigned int u32;
typedef float f32x4 __attribute__((ext_vector_type(4)));
typedef float f32x16 __attribute__((ext_vector_type(16)));
typedef __bf16 bf16x8 __attribute__((ext_vector_type(8)));
typedef __bf16 bf16x4 __attribute__((ext_vector_type(4)));
typedef unsigned short u16x4 __attribute__((ext_vector_type(4)));
typedef unsigned int u32x4v __attribute__((ext_vector_type(4)));

#define MFMA(a, b, c) __builtin_amdgcn_mfma_f32_16x16x32_bf16(a, b, c, 0, 0, 0)
#define MFMA32(a, b, c) __builtin_amdgcn_mfma_f32_32x32x16_bf16(a, b, c, 0, 0, 0)
#define EXP2(x) __builtin_amdgcn_exp2f(x)
#define LOG2E 1.44269504088896f

// XOR swizzle for 128-byte-stride LDS rows (bf16 [*][64]); returns BYTE offset.
__device__ __forceinline__ int swz(int row, int cb) { return row * 128 + (cb ^ ((row & 7) << 4)); }
// same for 256-byte-stride rows (bf16 [*][128])
__device__ __forceinline__ int swz256(int row, int cb) { return row * 256 + (cb ^ ((row & 7) << 4)); }

__device__ __forceinline__ float b2f(u16 v) {
    union { u32 u; float f; } x; x.u = ((u32)v) << 16; return x.f;
}

__device__ __forceinline__ u32 cvtpk(float lo, float hi) {
    u32 r;
    asm("v_cvt_pk_bf16_f32 %0, %1, %2" : "=v"(r) : "v"(lo), "v"(hi));
    return r;
}

// Build PV B-fragment (k=8*hi+e over a 16-m chunk) from 8 per-lane P values.
// lane<32 holds m{0..3}=p0..3, m{8..11}=p4..7; lane>=32 holds m{4..7}, m{12..15}.
__device__ __forceinline__ bf16x8 pfrag(float p0, float p1, float p2, float p3,
                                        float p4, float p5, float p6, float p7) {
    u32 x1 = cvtpk(p0, p1), x2 = cvtpk(p2, p3);
    u32 y1 = cvtpk(p4, p5), y2 = cvtpk(p6, p7);
    asm volatile("v_permlane32_swap_b32 %0, %1" : "+v"(x1), "+v"(y1));
    asm volatile("v_permlane32_swap_b32 %0, %1" : "+v"(x2), "+v"(y2));
    u32x4v d; d[0] = x1; d[1] = x2; d[2] = y1; d[3] = y2;
    return __builtin_bit_cast(bf16x8, d);
}

__device__ __forceinline__ bf16x8 cvt8(const float* p, float s) {
    f32x4 a = *(const f32x4*)p, b = *(const f32x4*)(p + 4);
    bf16x8 o;
    o[0] = (__bf16)(a[0] * s); o[1] = (__bf16)(a[1] * s);
    o[2] = (__bf16)(a[2] * s); o[3] = (__bf16)(a[3] * s);
    o[4] = (__bf16)(b[0] * s); o[5] = (__bf16)(b[1] * s);
    o[6] = (__bf16)(b[2] * s); o[7] = (__bf16)(b[3] * s);
    return o;
}

// ---------------------------------------------------------------------------
// Kernel 1: Q = (0.125*log2e)*wq*x ([B,N,C] bf16), K = wk*x ([B,N,C]),
// V = wv*x ([B,C,N]).  All D-fragments oriented so stores are bf16x4.
// ---------------------------------------------------------------------------
__global__ __launch_bounds__(256) void qkv_k(
    const float* __restrict__ x,
    const float* __restrict__ wq, const float* __restrict__ wk, const float* __restrict__ wv,
    const float* __restrict__ w1, const float* __restrict__ w2,
    u16* __restrict__ Qg, u16* __restrict__ Kg, u16* __restrict__ Vg,
    u16* __restrict__ w1b, u16* __restrict__ w2b)
{
    const int b = blockIdx.y, nt = blockIdx.x, t = threadIdx.x;
    const int lane = t & 63, wave = t >> 6, g = lane >> 4, r16 = lane & 15;
    __shared__ __align__(16) u16 xT[128 * 64];   // swizzled bf16 [n_local][c]
    const int n0 = nt * 128;

    bf16x8 wqf[4][2], wkf[4][2], wvf[4][2];
#pragma unroll
    for (int jt = 0; jt < 4; ++jt)
#pragma unroll
        for (int kc = 0; kc < 2; ++kc) {
            const int ro = (r16 + 16 * jt) * 64 + 8 * g + 32 * kc;
            wqf[jt][kc] = cvt8(wq + ro, 0.125f * LOG2E);  // fold 1/sqrt(C) and log2(e)
            wkf[jt][kc] = cvt8(wk + ro, 1.0f);
            wvf[jt][kc] = cvt8(wv + ro, 1.0f);
        }

    { // stage x tile transposed (n-major) + swizzled, as bf16
        int c = t >> 5;
        const int nn = (t & 31) * 4;
#pragma unroll
        for (int pass = 0; pass < 8; ++pass, c += 8) {
            f32x4 v = *(const f32x4*)&x[(size_t)(b * 64 + c) * 2048 + n0 + nn];
#pragma unroll
            for (int j = 0; j < 4; ++j)
                xT[swz(nn + j, 2 * c) >> 1] = __builtin_bit_cast(u16, (__bf16)v[j]);
        }
    }
    if (b == 0 && nt == 0) {
        for (int i = t; i < H_ * C_; i += 256) w1b[i] = __builtin_bit_cast(u16, (__bf16)w1[i]);
        for (int i = t; i < C_ * H_; i += 256) w2b[i] = __builtin_bit_cast(u16, (__bf16)w2[i]);
    }
    __syncthreads();

#pragma unroll
    for (int p = 0; p < 2; ++p) {
        const int nt16 = wave * 2 + p;
        bf16x8 xa[2];  // x^T tile frag: A (i=n) or B (j=n)
#pragma unroll
        for (int kc = 0; kc < 2; ++kc)
            xa[kc] = *(const bf16x8*)&xT[swz(nt16 * 16 + r16, 16 * g + 64 * kc) >> 1];
        // Q,K: D[o][n] -> row o = 16jt+4g+r, col n = r16 -> vector store along o
#pragma unroll
        for (int jt = 0; jt < 4; ++jt) {
            f32x4 aq = {0.f, 0.f, 0.f, 0.f}, ak = {0.f, 0.f, 0.f, 0.f};
            aq = MFMA(wqf[jt][0], xa[0], aq); aq = MFMA(wqf[jt][1], xa[1], aq);
            ak = MFMA(wkf[jt][0], xa[0], ak); ak = MFMA(wkf[jt][1], xa[1], ak);
            bf16x4 qk, kk;
#pragma unroll
            for (int r = 0; r < 4; ++r) { qk[r] = (__bf16)aq[r]; kk[r] = (__bf16)ak[r]; }
            const size_t ro = (size_t)(b * 2048 + n0 + nt16 * 16 + r16) * 64 + 16 * jt + 4 * g;
            *(bf16x4*)&Qg[ro] = qk;
            *(bf16x4*)&Kg[ro] = kk;
        }
        // V: D[n][o] -> row n = nt16*16+4g+r, col o = 16it+r16 -> vector store along n
#pragma unroll
        for (int it = 0; it < 4; ++it) {
            f32x4 av = {0.f, 0.f, 0.f, 0.f};
            av = MFMA(xa[0], wvf[it][0], av);
            av = MFMA(xa[1], wvf[it][1], av);
            bf16x4 vk;
#pragma unroll
            for (int r = 0; r < 4; ++r) vk[r] = (__bf16)av[r];
            *(bf16x4*)&Vg[(size_t)(b * 64 + 16 * it + r16) * 2048 + n0 + nt16 * 16 + 4 * g] = vk;
        }
    }
}

// ---------------------------------------------------------------------------
// Kernel 2: flash attention, 32x32x16 MFMA, fixed-shift softmax (exact).
// 512 blocks XCD-pinned, 4 waves x 32 q rows (q = lane&31, hi = lane>>5).
// K,V staged in LDS (32 KB dbuf, global_load_lds w=16, pre-swizzled source).
// T4 counted-vmcnt: raw s_barrier (no vmcnt drain) + s_waitcnt vmcnt(4) so
// the next tile's 4 prefetch loads stay in flight across the barrier.
// P = exp2(S - 12) (shift folded into QK C-init).  Row sum l via ones-MFMA.
// P -> PV B-frags via cvt_pk + permlane32_swap (register-only).
// Epilogue: y(bf16) = x + O/l + fused BN1 partials.
// ---------------------------------------------------------------------------
__global__ __launch_bounds__(256) void attn_k(
    const u16* __restrict__ Qg, const u16* __restrict__ Kg, const u16* __restrict__ Vg,
    const float* __restrict__ x, u16* __restrict__ yb,
    float* __restrict__ ps, float* __restrict__ pq)
{
    const int t = threadIdx.x;
    const int lane = t & 63, wave = t >> 6, q = lane & 31, hi = lane >> 5;
    const int L = blockIdx.x;              // 0..511
    const int xcd = L & 7, slot = L >> 3;  // slot 0..63
    const int b = xcd * 4 + (slot >> 4);
    const int qt = slot & 15;

    // bytes: K0@0, K1@8192, V0@16384, V1@24576.  32 KB total.
    __shared__ __align__(16) u16 Lds16[16384];
    char* lds = (char*)Lds16;

    const int n0 = qt * 128 + wave * 32;
    const int n = n0 + q;

    // Q B-frags: Q[q][c = 16kc + 8hi + e]
    bf16x8 qf[4];
    {
        const u16* qrow = Qg + (size_t)(b * 2048 + n) * 64 + 8 * hi;
#pragma unroll
        for (int kc = 0; kc < 4; ++kc)
            qf[kc] = *(const bf16x8*)(qrow + 16 * kc);
    }
    bf16x8 ones;
#pragma unroll
    for (int i = 0; i < 8; ++i) ones[i] = (__bf16)1.0f;

    f32x16 acc[2], accl;
#pragma unroll
    for (int r = 0; r < 16; ++r) { acc[0][r] = 0.f; acc[1][r] = 0.f; accl[r] = 0.f; }

    const char* Kgb = (const char*)Kg + (size_t)b * 2048 * 128;
    const char* Vgb = (const char*)Vg + (size_t)b * 64 * 4096;
    const int srcxor = (((lane & 7) ^ (lane >> 3)) << 4);
    const int rowb = wave * 16 + (lane >> 3);

    auto stage = [&](int kvt, int buf) {
#pragma unroll
        for (int j = 0; j < 2; ++j) {
            const char* gk = Kgb + (size_t)(kvt * 64 + rowb + 8 * j) * 128 + srcxor;
            const char* gv = Vgb + (size_t)(rowb + 8 * j) * 4096 + kvt * 128 + srcxor;
            char* lk = lds + buf * 8192 + (wave * 2 + j) * 1024;
            __builtin_amdgcn_global_load_lds(
                (const __attribute__((address_space(1))) void*)gk,
                (__attribute__((address_space(3))) void*)lk, 16, 0, 0);
            __builtin_amdgcn_global_load_lds(
                (const __attribute__((address_space(1))) void*)gv,
                (__attribute__((address_space(3))) void*)(lk + 16384), 16, 0, 0);
        }
    };

    auto tile = [&](int kvt, int buf, bool last) {
        // T4: raw barrier (no vmcnt drain); all LDS reads of the previous tile
        // were consumed by MFMAs (compiler-awaited), drain lgkm explicitly.
        asm volatile("s_waitcnt lgkmcnt(0)" ::: "memory");
        __builtin_amdgcn_sched_barrier(0);
        __builtin_amdgcn_s_barrier();
        __builtin_amdgcn_sched_barrier(0);
        if (!last) {
            stage(kvt + 1, buf ^ 1);     // 4 loads -> in flight across compute
            asm volatile("s_waitcnt vmcnt(4)" ::: "memory");   // tile-t loads done
        } else {
            asm volatile("s_waitcnt vmcnt(0)" ::: "memory");
        }
        __builtin_amdgcn_sched_barrier(0);
        const char* Kc = lds + buf * 8192;
        const char* Vc = Kc + 16384;

        // QK^T, C-init = -MSHIFT: st = S - 12 directly (log2 domain)
        f32x16 st[2];
        __builtin_amdgcn_s_setprio(1);
#pragma unroll
        for (int it = 0; it < 2; ++it) {
            f32x16 a;
#pragma unroll
            for (int r = 0; r < 16; ++r) a[r] = -MSHIFT;
#pragma unroll
            for (int kc = 0; kc < 4; ++kc) {
                bf16x8 kf = *(const bf16x8*)(Kc + swz(32 * it + q, 32 * kc + 16 * hi));
                a = MFMA32(kf, qf[kc], a);
            }
            st[it] = a;
        }
        __builtin_amdgcn_s_setprio(0);

        // V A-frags: V^T[c = 32ct+q][m = 16mc + 8hi + e]
        bf16x8 vf[2][4];
#pragma unroll
        for (int ct = 0; ct < 2; ++ct)
#pragma unroll
            for (int mc = 0; mc < 4; ++mc)
                vf[ct][mc] = *(const bf16x8*)(Vc + swz(32 * ct + q, 32 * mc + 16 * hi));

        // P = exp2(S - 12): starts immediately, no max/rescale dependency
#pragma unroll
        for (int it = 0; it < 2; ++it)
#pragma unroll
            for (int r = 0; r < 16; ++r) st[it][r] = EXP2(st[it][r]);

        // P B-frags: register-only (cvt_pk + permlane32_swap)
        bf16x8 pf0 = pfrag(st[0][0], st[0][1], st[0][2], st[0][3],
                           st[0][4], st[0][5], st[0][6], st[0][7]);
        bf16x8 pf1 = pfrag(st[0][8], st[0][9], st[0][10], st[0][11],
                           st[0][12], st[0][13], st[0][14], st[0][15]);
        bf16x8 pf2 = pfrag(st[1][0], st[1][1], st[1][2], st[1][3],
                           st[1][4], st[1][5], st[1][6], st[1][7]);
        bf16x8 pf3 = pfrag(st[1][8], st[1][9], st[1][10], st[1][11],
                           st[1][12], st[1][13], st[1][14], st[1][15]);
        __builtin_amdgcn_s_setprio(1);
#pragma unroll
        for (int ct = 0; ct < 2; ++ct) {
            acc[ct] = MFMA32(vf[ct][0], pf0, acc[ct]);
            acc[ct] = MFMA32(vf[ct][1], pf1, acc[ct]);
            acc[ct] = MFMA32(vf[ct][2], pf2, acc[ct]);
            acc[ct] = MFMA32(vf[ct][3], pf3, acc[ct]);
        }
        // row sum l via ones-MFMA: accl[any r] accumulates sum_m P[m][q]
        accl = MFMA32(ones, pf0, accl);
        accl = MFMA32(ones, pf1, accl);
        accl = MFMA32(ones, pf2, accl);
        accl = MFMA32(ones, pf3, accl);
        __builtin_amdgcn_s_setprio(0);
    };

    stage(0, 0);
#pragma unroll 1
    for (int kvt = 0; kvt < 30; kvt += 2) {
        tile(kvt, 0, false);
        tile(kvt + 1, 1, false);
    }
    tile(30, 0, false);
    tile(31, 1, true);

    // epilogue: l complete in accl[0] (all 64 m's per tile, all tiles)
    const float inv = 1.0f / accl[0];
    float sv[2][16], qv[2][16];
#pragma unroll
    for (int ct = 0; ct < 2; ++ct)
#pragma unroll
        for (int r = 0; r < 16; ++r) {
            const int c = 32 * ct + (r & 3) + 8 * (r >> 2) + 4 * hi;
            const float o = acc[ct][r] * inv + x[(size_t)(b * 64 + c) * 2048 + n];
            sv[ct][r] = o;
            qv[ct][r] = o * o;
        }
#pragma unroll
    for (int ct = 0; ct < 2; ++ct)
#pragma unroll
        for (int grp = 0; grp < 4; ++grp) {
            bf16x4 ov;
#pragma unroll
            for (int r = 0; r < 4; ++r) ov[r] = (__bf16)sv[ct][4 * grp + r];
            *(bf16x4*)&yb[(size_t)(b * 2048 + n) * 64 + 32 * ct + 8 * grp + 4 * hi] = ov;
        }
    // reduce stats over the wave's 32 q rows (across lane&31; hi kept separate)
#pragma unroll
    for (int d = 1; d <= 16; d <<= 1)
#pragma unroll
        for (int ct = 0; ct < 2; ++ct)
#pragma unroll
            for (int r = 0; r < 16; ++r) {
                sv[ct][r] += __shfl_xor(sv[ct][r], d, 64);
                qv[ct][r] += __shfl_xor(qv[ct][r], d, 64);
            }
    __syncthreads();                       // K/V buffers no longer needed
    float* sb = (float*)lds;               // [0..255]=sum, [256..511]=sumsq
    if (q == 0) {
#pragma unroll
        for (int ct = 0; ct < 2; ++ct)
#pragma unroll
            for (int r = 0; r < 16; ++r) {
                const int c = 32 * ct + (r & 3) + 8 * (r >> 2) + 4 * hi;
                sb[wave * 64 + c] = sv[ct][r];
                sb[256 + wave * 64 + c] = qv[ct][r];
            }
    }
    __syncthreads();
    if (t < 64) {
        ps[L * 64 + t] = sb[t] + sb[64 + t] + sb[128 + t] + sb[192 + t];
        pq[L * 64 + t] = sb[256 + t] + sb[320 + t] + sb[384 + t] + sb[448 + t];
    }
}

// ---------------------------------------------------------------------------
// finalize: 64 blocks (one channel each) sum nblk partials -> scale/shift
// ---------------------------------------------------------------------------
__global__ __launch_bounds__(256) void finalize_k(
    const float* __restrict__ psum, const float* __restrict__ psq,
    const float* __restrict__ gamma, const float* __restrict__ beta,
    float* __restrict__ ss, int nblk)
{
    const int c = blockIdx.x, t = threadIdx.x;
    const int lane = t & 63, wave = t >> 6;
    float s = 0.f, q = 0.f;
    for (int bl = t; bl < nblk; bl += 256) {
        s += psum[bl * 64 + c];
        q += psq[bl * 64 + c];
    }
#pragma unroll
    for (int d = 1; d <= 32; d <<= 1) {
        s += __shfl_xor(s, d, 64);
        q += __shfl_xor(q, d, 64);
    }
    __shared__ float ls[4], lq[4];
    if (lane == 0) { ls[wave] = s; lq[wave] = q; }
    __syncthreads();
    if (t == 0) {
        s = ls[0] + ls[1] + ls[2] + ls[3];
        q = lq[0] + lq[1] + lq[2] + lq[3];
        const float mean = s * (1.0f / 65536.0f);
        const float var  = q * (1.0f / 65536.0f) - mean * mean;
        const float sc   = rsqrtf(var + 1e-5f) * gamma[c];
        ss[c] = sc;
        ss[64 + c] = beta[c] - mean * sc;
    }
}

// ---------------------------------------------------------------------------
// Kernel: h = BN1(y_bf16); ff = W2 * lrelu(W1 * h); z(bf16) = h + ff
// plus fused BN2 partial sums (from exact f32 registers).
// ---------------------------------------------------------------------------
__global__ __launch_bounds__(256) void ff_k(
    const u16* __restrict__ y, const float* __restrict__ ss1,
    const u16* __restrict__ w1b, const u16* __restrict__ w2b,
    u16* __restrict__ zb, float* __restrict__ ps, float* __restrict__ pq)
{
    const int b = blockIdx.y, nt = blockIdx.x, t = threadIdx.x;
    const int lane = t & 63, wave = t >> 6, g = lane >> 4, r16 = lane & 15;
    const int L = blockIdx.y * gridDim.x + blockIdx.x;
    __shared__ __align__(16) u16 hT[64 * 64];       // swizzled bf16 [n][c]
    __shared__ __align__(16) float hf[64 * 68];     // f32 [n][c], pad 68
    __shared__ __align__(16) u16 pb[4][16 * 128];   // per-wave swizzled [n][h]
    __shared__ float sc1[64], sh1[64];
    if (t < 64) { sc1[t] = ss1[t]; sh1[t] = ss1[64 + t]; }
    __syncthreads();
    const int n0 = nt * 64;
    {
        const int i = t >> 2, c0 = (t & 3) * 16;
        u16 yb16[16] __attribute__((aligned(16)));
        *(uint4*)&yb16[0] = *(const uint4*)&y[(size_t)(b * 2048 + n0 + i) * 64 + c0];
        *(uint4*)&yb16[8] = *(const uint4*)&y[(size_t)(b * 2048 + n0 + i) * 64 + c0 + 8];
        u16 hb[16] __attribute__((aligned(16)));
#pragma unroll
        for (int q4 = 0; q4 < 4; ++q4) {
            f32x4 hv;
#pragma unroll
            for (int j = 0; j < 4; ++j) {
                const int c = c0 + 4 * q4 + j;
                hv[j] = b2f(yb16[4 * q4 + j]) * sc1[c] + sh1[c];
                hb[4 * q4 + j] = __builtin_bit_cast(u16, (__bf16)hv[j]);
            }
            *(f32x4*)&hf[i * 68 + c0 + 4 * q4] = hv;
        }
        *(uint4*)&hT[swz(i, 2 * c0) >> 1]      = *(const uint4*)&hb[0];
        *(uint4*)&hT[swz(i, 2 * c0 + 16) >> 1] = *(const uint4*)&hb[8];
    }
    __syncthreads();

    bf16x8 ha[2];
#pragma unroll
    for (int kc = 0; kc < 2; ++kc)
        ha[kc] = *(const bf16x8*)&hT[swz(wave * 16 + r16, 16 * g + 64 * kc) >> 1];
    // ff1 = lrelu(W1 * h), written transposed to pb
#pragma unroll
    for (int it = 0; it < 8; ++it) {
        f32x4 a = {0.f, 0.f, 0.f, 0.f};
#pragma unroll
        for (int kc = 0; kc < 2; ++kc) {
            bf16x8 w1f = *(const bf16x8*)&w1b[(r16 + 16 * it) * 64 + 8 * g + 32 * kc];
            a = MFMA(w1f, ha[kc], a);
        }
        u16x4 pk;
#pragma unroll
        for (int r = 0; r < 4; ++r) {
            const float rv = a[r] >= 0.f ? a[r] : 0.2f * a[r];
            pk[r] = __builtin_bit_cast(u16, (__bf16)rv);
        }
        *(u16x4*)&pb[wave][swz256(r16, 2 * (16 * it + 4 * g)) >> 1] = pk;
    }
    // ff2: D[c][n] (A=w2f, B=pa) -> vector store along c; z = h + ff2
    bf16x8 pa[4];
#pragma unroll
    for (int kc = 0; kc < 4; ++kc)
        pa[kc] = *(const bf16x8*)&pb[wave][swz256(r16, 16 * g + 64 * kc) >> 1];
    const int nl = wave * 16 + r16;
    float sv[4][4], qv[4][4];
#pragma unroll
    for (int jt = 0; jt < 4; ++jt) {
        f32x4 a = {0.f, 0.f, 0.f, 0.f};
#pragma unroll
        for (int kc = 0; kc < 4; ++kc) {
            bf16x8 w2f = *(const bf16x8*)&w2b[(r16 + 16 * jt) * 128 + 8 * g + 32 * kc];
            a = MFMA(w2f, pa[kc], a);
        }
        f32x4 h4 = *(const f32x4*)&hf[nl * 68 + 16 * jt + 4 * g];
        bf16x4 zk;
#pragma unroll
        for (int r = 0; r < 4; ++r) {
            a[r] += h4[r];
            sv[jt][r] = a[r];
            qv[jt][r] = a[r] * a[r];
            zk[r] = (__bf16)a[r];
        }
        *(bf16x4*)&zb[(size_t)(b * 2048 + n0 + nl) * 64 + 16 * jt + 4 * g] = zk;
    }
    // fused BN2 partials: reduce over the wave's 16 rows (across r16)
#pragma unroll
    for (int d = 1; d <= 8; d <<= 1)
#pragma unroll
        for (int jt = 0; jt < 4; ++jt)
#pragma unroll
            for (int r = 0; r < 4; ++r) {
                sv[jt][r] += __shfl_xor(sv[jt][r], d, 64);
                qv[jt][r] += __shfl_xor(qv[jt][r], d, 64);
            }
    __syncthreads();                       // all waves done with pb
    float* sb = (float*)&pb[0][0];
    if (r16 == 0) {
#pragma unroll
        for (int jt = 0; jt < 4; ++jt)
#pragma unroll
            for (int r = 0; r < 4; ++r) {
                const int c = 16 * jt + 4 * g + r;
                sb[wave * 64 + c] = sv[jt][r];
                sb[256 + wave * 64 + c] = qv[jt][r];
            }
    }
    __syncthreads();
    if (t < 64) {
        ps[L * 64 + t] = sb[t] + sb[64 + t] + sb[128 + t] + sb[192 + t];
        pq[L * 64 + t] = sb[256 + t] + sb[320 + t] + sb[384 + t] + sb[448 + t];
    }
}

// ---------------------------------------------------------------------------
// Kernel: out[B,C,N] = BN2(z_bf16[B,N,C])  (LDS transpose, f32 output)
// ---------------------------------------------------------------------------
__global__ __launch_bounds__(256) void bnout_k(
    const u16* __restrict__ zb, const float* __restrict__ ss2, float* __restrict__ out)
{
    const int b = blockIdx.y, nt = blockIdx.x, t = threadIdx.x;
    __shared__ float tile[64 * 68];
    __shared__ float sc2[64], sh2[64];
    if (t < 64) { sc2[t] = ss2[t]; sh2[t] = ss2[64 + t]; }
    __syncthreads();
    const int n0 = nt * 64;
    {
        const int i = t >> 2, c0 = (t & 3) * 16;
        u16 zb16[16] __attribute__((aligned(16)));
        *(uint4*)&zb16[0] = *(const uint4*)&zb[(size_t)(b * 2048 + n0 + i) * 64 + c0];
        *(uint4*)&zb16[8] = *(const uint4*)&zb[(size_t)(b * 2048 + n0 + i) * 64 + c0 + 8];
#pragma unroll
        for (int q4 = 0; q4 < 4; ++q4) {
            f32x4 tv;
#pragma unroll
            for (int j = 0; j < 4; ++j) {
                const int c = c0 + 4 * q4 + j;
                tv[j] = b2f(zb16[4 * q4 + j]) * sc2[c] + sh2[c];
            }
            *(f32x4*)&tile[i * 68 + c0 + 4 * q4] = tv;
        }
    }
    __syncthreads();
    {
        const int c = t >> 2, j0 = (t & 3) * 16;
#pragma unroll
        for (int q4 = 0; q4 < 4; ++q4) {
            f32x4 ov;
#pragma unroll
            for (int j = 0; j < 4; ++j)
                ov[j] = tile[(j0 + 4 * q4 + j) * 68 + c];
            *(f32x4*)&out[(size_t)(b * 64 + c) * 2048 + n0 + j0 + 4 * q4] = ov;
        }
    }
}

extern "C" void kernel_launch(void* const* d_in, const int* in_sizes, int n_in,
                              void* d_out, int out_size, void* d_ws, size_t ws_size,
                              hipStream_t stream)
{
    const float* x   = (const float*)d_in[0];
    const float* wq  = (const float*)d_in[1];
    const float* wk  = (const float*)d_in[2];
    const float* wv  = (const float*)d_in[3];
    const float* w1  = (const float*)d_in[4];
    const float* w2  = (const float*)d_in[5];
    const float* g1  = (const float*)d_in[6];
    const float* be1 = (const float*)d_in[7];
    const float* g2  = (const float*)d_in[8];
    const float* be2 = (const float*)d_in[9];
    float* out = (float*)d_out;

    char* w = (char*)d_ws;
    u16* Qg = (u16*)w;   w += (size_t)B_ * N_ * C_ * 2;
    u16* Kg = (u16*)w;   w += (size_t)B_ * N_ * C_ * 2;
    u16* Vg = (u16*)w;   w += (size_t)B_ * N_ * C_ * 2;
    u16* yb = (u16*)w;   w += (size_t)B_ * N_ * C_ * 2;
    u16* zb = (u16*)w;   w += (size_t)B_ * N_ * C_ * 2;
    u16* w1b = (u16*)w;  w += (size_t)H_ * C_ * 2;
    u16* w2b = (u16*)w;  w += (size_t)C_ * H_ * 2;
    float* ps1 = (float*)w; w += 1024 * 64 * 4;
    float* pq1 = (float*)w; w += 1024 * 64 * 4;
    float* ps2 = (float*)w; w += 1024 * 64 * 4;
    float* pq2 = (float*)w; w += 1024 * 64 * 4;
    float* ss1 = (float*)w; w += 128 * 4;
    float* ss2 = (float*)w; w += 128 * 4;

    const dim3 blk(256);
    hipLaunchKernelGGL(qkv_k,   dim3(16, 32), blk, 0, stream, x, wq, wk, wv, w1, w2, Qg, Kg, Vg, w1b, w2b);
    hipLaunchKernelGGL(attn_k,  dim3(512),    blk, 0, stream, Qg, Kg, Vg, x, yb, ps1, pq1);
    hipLaunchKernelGGL(finalize_k, dim3(64),  blk, 0, stream, ps1, pq1, g1, be1, ss1, 512);
    hipLaunchKernelGGL(ff_k,    dim3(32, 32), blk, 0, stream, yb, ss1, w1b, w2b, zb, ps2, pq2);
    hipLaunchKernelGGL(finalize_k, dim3(64),  blk, 0, stream, ps2, pq2, g2, be2, ss2, 1024);
    hipLaunchKernelGGL(bnout_k, dim3(32, 32), blk, 0, stream, zb, ss2, out);
}